// Round 7
// baseline (184.952 us; speedup 1.0000x reference)
//
#include <hip/hip_runtime.h>

#define B_ 4
#define C_ 64
#define H_ 256
#define W_ 256
#define HW_ (H_*W_)
#define MID_ 12
#define NPB_ 256   // gap partial slots per image (= blocks per image)

__device__ __forceinline__ float wave_reduce64(float v) {
#pragma unroll
    for (int off = 32; off; off >>= 1) v += __shfl_xor(v, off, 64);
    return v;
}

__device__ __forceinline__ void fnorm9(float* t9, const float* __restrict__ sstd) {
    float mean = 0.f;
#pragma unroll
    for (int t = 0; t < 9; ++t) mean += t9[t];
    mean *= (1.f / 9.f);
    float var = 0.f;
#pragma unroll
    for (int t = 0; t < 9; ++t) { float d = t9[t] - mean; var += d * d; }
    float inv = 1.f / (sqrtf(var * (1.f / 8.f)) + 1e-10f);
#pragma unroll
    for (int t = 0; t < 9; ++t) t9[t] = (t9[t] - mean) * inv * sstd[t];
}

// ---------------- prep: read x once -> s1 + gap1 partials ----------------
// block 256 = 4 waves; lane -> col (64-strip), wave -> row. grid (4, 64, B) = 1024.
__global__ __launch_bounds__(256) void prep_kernel(const float* __restrict__ x,
    const float* __restrict__ sw, const float* __restrict__ sb,
    const float* __restrict__ sstd, float* __restrict__ sarr, float* __restrict__ gp) {
    const int lane = threadIdx.x & 63, wv = threadIdx.x >> 6;
    const int col = blockIdx.x * 64 + lane;
    const int row = blockIdx.y * 4 + wv;
    const int b = blockIdx.z;
    const int bslot = blockIdx.y * gridDim.x + blockIdx.x;  // 0..NPB_-1
    const int pix = row * W_ + col;
    __shared__ float lg[4][C_];

    float st[9];
#pragma unroll
    for (int t = 0; t < 9; ++t) st[t] = sb[t];

    const float* xb = x + (size_t)b * C_ * HW_;   // wave-uniform base
    float vA[8], vB[8];
#pragma unroll
    for (int i = 0; i < 8; ++i) vA[i] = xb[(size_t)i * HW_ + pix];

    for (int c8 = 0; c8 < C_; c8 += 16) {
#pragma unroll
        for (int i = 0; i < 8; ++i) vB[i] = xb[(size_t)(c8 + 8 + i) * HW_ + pix];
#pragma unroll
        for (int i = 0; i < 8; ++i) {
#pragma unroll
            for (int t = 0; t < 9; ++t) st[t] = fmaf(vA[i], sw[t * C_ + c8 + i], st[t]);
            float g = wave_reduce64(vA[i]);
            if (lane == 0) lg[wv][c8 + i] = g;
        }
        if (c8 + 16 < C_) {
#pragma unroll
            for (int i = 0; i < 8; ++i) vA[i] = xb[(size_t)(c8 + 16 + i) * HW_ + pix];
        }
#pragma unroll
        for (int i = 0; i < 8; ++i) {
#pragma unroll
            for (int t = 0; t < 9; ++t) st[t] = fmaf(vB[i], sw[t * C_ + c8 + 8 + i], st[t]);
            float g = wave_reduce64(vB[i]);
            if (lane == 0) lg[wv][c8 + 8 + i] = g;
        }
    }
    fnorm9(st, sstd);
    {
        float* sp = sarr + ((size_t)b * 9) * HW_ + pix;
#pragma unroll
        for (int t = 0; t < 9; ++t) sp[(size_t)t * HW_] = st[t];
    }
    __syncthreads();
    if (threadIdx.x < C_) {
        int c = threadIdx.x;
        float s4 = lg[0][c] + lg[1][c] + lg[2][c] + lg[3][c];
        gp[((size_t)b * C_ + c) * NPB_ + bslot] = s4;
    }
}

// ------ cfk: reduce gap partials + SE MLP + FilterNorm -> cf (B,C,12 padded) ------
__global__ __launch_bounds__(256) void cfk(const float* __restrict__ gp,
    const float* __restrict__ cw1, const float* __restrict__ cb1,
    const float* __restrict__ cw2, const float* __restrict__ cb2,
    const float* __restrict__ cstd, float* __restrict__ cf) {
    const int tid = threadIdx.x;
    const int b = tid >> 6, c = tid & 63;
    __shared__ float gsm[B_][C_];
    __shared__ float hsm[B_][MID_];
    {
        const float4* p4 = (const float4*)(gp + ((size_t)b * C_ + c) * NPB_);
        float s = 0.f;
#pragma unroll 4
        for (int i = 0; i < NPB_ / 4; ++i) { float4 v = p4[i]; s += (v.x + v.y) + (v.z + v.w); }
        gsm[b][c] = s * (1.f / HW_);
    }
    __syncthreads();
    if (tid < B_ * MID_) {
        int b2 = tid / MID_, m = tid % MID_;
        float a = cb1[m];
        for (int cc = 0; cc < C_; ++cc) a = fmaf(gsm[b2][cc], cw1[m * C_ + cc], a);
        hsm[b2][m] = fmaxf(a, 0.f);
    }
    __syncthreads();
    float v[9];
    float mean = 0.f;
#pragma unroll
    for (int t = 0; t < 9; ++t) {
        int o = c * 9 + t;
        float a = cb2[o];
#pragma unroll
        for (int m = 0; m < MID_; ++m) a = fmaf(hsm[b][m], cw2[o * MID_ + m], a);
        v[t] = a;
        mean += a;
    }
    mean *= (1.f / 9.f);
    float var = 0.f;
#pragma unroll
    for (int t = 0; t < 9; ++t) { float d = v[t] - mean; var += d * d; }
    float inv = 1.f / (sqrtf(var * (1.f / 8.f)) + 1e-10f);
    float* o12 = cf + ((size_t)b * C_ + c) * 12;
#pragma unroll
    for (int t = 0; t < 9; ++t) o12[t] = (v[t] - mean) * inv * cstd[c * 9 + t];
    o12[9] = 0.f; o12[10] = 0.f; o12[11] = 0.f;
}

// ---------- apply: LDS-staged 3x3 dynamic filter ----------
// Tile 64x4 px, all 64 channels in 8-channel chunks; halo tile (6 rows x 66 cols)
// per channel staged via regs->LDS double buffer. OOB pre-zeroed in LDS.
// grid (256, B). XCD-swizzled tile mapping.
template<bool PASS1>
__global__ __launch_bounds__(256) void apply_kernel(const float* __restrict__ in,
    const float* __restrict__ sarr, const float* __restrict__ cf,
    const float* __restrict__ swn, const float* __restrict__ sbn,
    const float* __restrict__ sstdn, const float* __restrict__ resid,
    float* __restrict__ out, float* __restrict__ snext, float* __restrict__ gpn) {
    const int tid = threadIdx.x;
    const int lane = tid & 63, wv = tid >> 6;
    const int f = blockIdx.x;                 // 0..255 (dispatch order)
    const int b = blockIdx.y;
    const int swz = (f & 7) * 32 + (f >> 3);  // bijective: each XCD -> 32-row band
    const int bx = swz & 3, by = swz >> 2;
    const int col0 = bx * 64, row0 = by * 4;
    const int col = col0 + lane, row = row0 + wv;
    const int pix = row * W_ + col;

    __shared__ float sm[2][8][6][68];         // 26112 B
    __shared__ float lg[4][C_];

    // chunk-invariant staging slots: 8ch x 6rows x 66cols = 3168 elems, 13/thread
    int goff[13]; float gmask[13]; int loff[13];
#pragma unroll
    for (int j = 0; j < 13; ++j) {
        int i = tid + j * 256;
        int ch = i / 396; int rem = i - ch * 396;
        int rr = rem / 66; int cx = rem - rr * 66;
        int gr = row0 - 1 + rr, gc = col0 - 1 + cx;
        bool valid = i < 3168;
        bool ok = valid && (gr >= 0) && (gr < H_) && (gc >= 0) && (gc < W_);
        goff[j] = ok ? (ch * HW_ + gr * W_ + gc) : 0;
        gmask[j] = ok ? 1.f : 0.f;
        loff[j] = valid ? (ch * 408 + rr * 68 + cx) : -1;
    }

    // s at my pixel (9 taps) — OOB handled by zeros in LDS, no mask needed
    float s0[9];
    {
        const float* sp = sarr + ((size_t)b * 9) * HW_ + pix;
#pragma unroll
        for (int t = 0; t < 9; ++t) s0[t] = sp[(size_t)t * HW_];
    }
    float nt[9];
    if (PASS1) {
#pragma unroll
        for (int t = 0; t < 9; ++t) nt[t] = sbn[t];
    }

    const float* inb = in + (size_t)b * C_ * HW_;
    const float* cfb = cf + ((size_t)b * C_) * 12;
    const float* rb  = PASS1 ? nullptr : (resid + (size_t)b * C_ * HW_);
    float* outp = out + (size_t)b * C_ * HW_;

    float rstg[13], rv[8];

#define STAGE_LOAD(CH0) do {                                              \
        const float* cb_ = inb + (size_t)(CH0) * HW_;                     \
        _Pragma("unroll")                                                 \
        for (int j_ = 0; j_ < 13; ++j_) rstg[j_] = cb_[goff[j_]] * gmask[j_]; \
    } while (0)

#define STAGE_WRITE(BUFI) do {                                            \
        float* sb_ = &sm[BUFI][0][0][0];                                  \
        _Pragma("unroll")                                                 \
        for (int j_ = 0; j_ < 13; ++j_)                                   \
            if (loff[j_] >= 0) sb_[loff[j_]] = rstg[j_];                  \
    } while (0)

#define CHUNK_COMPUTE(BUFI, CH0) do {                                     \
        _Pragma("unroll")                                                 \
        for (int c_ = 0; c_ < 8; ++c_) {                                  \
            const float* cfc_ = cfb + (size_t)((CH0) + c_) * 12;          \
            float acc_ = 0.f;                                             \
            _Pragma("unroll")                                             \
            for (int dr_ = 0; dr_ < 3; ++dr_)                             \
                _Pragma("unroll")                                         \
                for (int dc_ = 0; dc_ < 3; ++dc_) {                       \
                    const int t_ = dr_ * 3 + dc_;                         \
                    acc_ = fmaf(sm[BUFI][c_][wv + dr_][lane + dc_] * s0[t_], \
                                cfc_[t_], acc_);                          \
                }                                                         \
            float o_;                                                     \
            if (PASS1) {                                                  \
                o_ = fmaxf(acc_, 0.f);                                    \
                _Pragma("unroll")                                         \
                for (int t_ = 0; t_ < 9; ++t_)                            \
                    nt[t_] = fmaf(o_, swn[t_ * C_ + (CH0) + c_], nt[t_]); \
                float g_ = wave_reduce64(o_);                             \
                if (lane == 0) lg[wv][(CH0) + c_] = g_;                   \
            } else {                                                      \
                o_ = acc_ + rv[c_];                                       \
            }                                                             \
            outp[(size_t)((CH0) + c_) * HW_ + pix] = o_;                  \
        }                                                                 \
    } while (0)

    STAGE_LOAD(0);
    STAGE_WRITE(0);
    __syncthreads();

#pragma unroll
    for (int k = 0; k < 8; ++k) {
        const int ch0 = k * 8;
        if (k < 7) STAGE_LOAD(ch0 + 8);
        if (!PASS1) {
#pragma unroll
            for (int c = 0; c < 8; ++c) rv[c] = rb[(size_t)(ch0 + c) * HW_ + pix];
        }
        if (k & 1) CHUNK_COMPUTE(1, ch0); else CHUNK_COMPUTE(0, ch0);
        if (k < 7) {
            __syncthreads();
            if (k & 1) STAGE_WRITE(0); else STAGE_WRITE(1);
            __syncthreads();
        }
    }
#undef STAGE_LOAD
#undef STAGE_WRITE
#undef CHUNK_COMPUTE

    if (PASS1) {
        fnorm9(nt, sstdn);
        {
            float* sp = snext + ((size_t)b * 9) * HW_ + pix;
#pragma unroll
            for (int t = 0; t < 9; ++t) sp[(size_t)t * HW_] = nt[t];
        }
        __syncthreads();
        if (tid < C_) {
            int c = tid;
            float s4 = lg[0][c] + lg[1][c] + lg[2][c] + lg[3][c];
            gpn[((size_t)b * C_ + c) * NPB_ + f] = s4;
        }
    }
}

extern "C" void kernel_launch(void* const* d_in, const int* in_sizes, int n_in,
                              void* d_out, int out_size, void* d_ws, size_t ws_size,
                              hipStream_t stream) {
    const float* x     = (const float*)d_in[0];
    const float* sw1   = (const float*)d_in[1];
    const float* sb1   = (const float*)d_in[2];
    const float* sstd1 = (const float*)d_in[3];
    const float* cw1_1 = (const float*)d_in[4];
    const float* cb1_1 = (const float*)d_in[5];
    const float* cw2_1 = (const float*)d_in[6];
    const float* cb2_1 = (const float*)d_in[7];
    const float* cstd1 = (const float*)d_in[8];
    const float* sw2   = (const float*)d_in[9];
    const float* sb2   = (const float*)d_in[10];
    const float* sstd2 = (const float*)d_in[11];
    const float* cw1_2 = (const float*)d_in[12];
    const float* cb1_2 = (const float*)d_in[13];
    const float* cw2_2 = (const float*)d_in[14];
    const float* cb2_2 = (const float*)d_in[15];
    const float* cstd2 = (const float*)d_in[16];
    float* outp = (float*)d_out;

    const size_t n_out1 = (size_t)B_ * C_ * HW_;     // 16,777,216
    const size_t n_s    = (size_t)B_ * 9 * HW_;      // 2,359,296
    const size_t n_cf   = (size_t)B_ * C_ * 12;      // 3,072 (padded)
    const size_t n_gp   = (size_t)B_ * C_ * NPB_;    // 65,536
    const size_t need = (n_out1 + 2 * n_s + 2 * n_cf + 2 * n_gp) * sizeof(float);
    if (ws_size < need) return;

    float* out1 = (float*)d_ws;
    float* s1   = out1 + n_out1;
    float* s2   = s1 + n_s;
    float* cf1  = s2 + n_s;
    float* cf2  = cf1 + n_cf;
    float* gp1  = cf2 + n_cf;
    float* gp2  = gp1 + n_gp;

    dim3 gp_(W_ / 64, H_ / 4, B_);   // prep: 1024 blocks
    dim3 ga(256, B_);                // apply: 1024 blocks (2-D, swizzled inside)

    prep_kernel<<<gp_, 256, 0, stream>>>(x, sw1, sb1, sstd1, s1, gp1);
    cfk<<<1, 256, 0, stream>>>(gp1, cw1_1, cb1_1, cw2_1, cb2_1, cstd1, cf1);
    apply_kernel<true><<<ga, 256, 0, stream>>>(x, s1, cf1, sw2, sb2, sstd2,
                                               nullptr, out1, s2, gp2);
    cfk<<<1, 256, 0, stream>>>(gp2, cw1_2, cb1_2, cw2_2, cb2_2, cstd2, cf2);
    apply_kernel<false><<<ga, 256, 0, stream>>>(out1, s2, cf2, nullptr, nullptr,
                                                nullptr, x, outp, nullptr, nullptr);
}

// Round 8
// 151.305 us; speedup vs baseline: 1.2224x; 1.2224x over previous
//
#include <hip/hip_runtime.h>

#define B_ 4
#define C_ 64
#define H_ 256
#define W_ 256
#define HW_ (H_*W_)
#define MID_ 12
#define NPB_ 64   // gap partial slots per image (= row-blocks per image: H/4)

__device__ __forceinline__ float wave_reduce64(float v) {
#pragma unroll
    for (int off = 32; off; off >>= 1) v += __shfl_xor(v, off, 64);
    return v;
}

// ---------------- prep: read x once -> s1 + gap1 partials ----------------
// wave = one full row (64 lanes x 4 px); block = 4 waves = 4 rows. grid (64, B).
__global__ __launch_bounds__(256, 1) void prep_kernel(const float* __restrict__ x,
    const float* __restrict__ sw, const float* __restrict__ sb,
    const float* __restrict__ sstd, float* __restrict__ sarr, float* __restrict__ gp) {
    const int lane = threadIdx.x & 63, wv = threadIdx.x >> 6;
    const int row = blockIdx.x * 4 + wv;
    const int b = blockIdx.y;
    const int pix = row * W_ + lane * 4;
    __shared__ float lg[4][C_];

    float4 st[9];
#pragma unroll
    for (int t = 0; t < 9; ++t) { float v = sb[t]; st[t] = make_float4(v, v, v, v); }

    const float* xb = x + (size_t)b * C_ * HW_ + pix;
    float4 vA[4], vB[4];
#pragma unroll
    for (int i = 0; i < 4; ++i) vA[i] = *(const float4*)(xb + (size_t)i * HW_);

#define PREP_COMP(BUF, C0) do {                                               \
        _Pragma("unroll")                                                     \
        for (int i_ = 0; i_ < 4; ++i_) {                                      \
            const int c_ = (C0) + i_;                                         \
            float4 v_ = BUF[i_];                                              \
            _Pragma("unroll")                                                 \
            for (int t_ = 0; t_ < 9; ++t_) {                                  \
                const float wt_ = sw[t_ * C_ + c_];                           \
                st[t_].x = fmaf(v_.x, wt_, st[t_].x);                         \
                st[t_].y = fmaf(v_.y, wt_, st[t_].y);                         \
                st[t_].z = fmaf(v_.z, wt_, st[t_].z);                         \
                st[t_].w = fmaf(v_.w, wt_, st[t_].w);                         \
            }                                                                 \
            float g_ = wave_reduce64(((v_.x + v_.y) + (v_.z + v_.w)));        \
            if (lane == 0) lg[wv][c_] = g_;                                   \
        }                                                                     \
    } while (0)

    for (int k = 0; k < C_; k += 8) {
#pragma unroll
        for (int i = 0; i < 4; ++i) vB[i] = *(const float4*)(xb + (size_t)(k + 4 + i) * HW_);
        PREP_COMP(vA, k);
        if (k + 8 < C_) {
#pragma unroll
            for (int i = 0; i < 4; ++i) vA[i] = *(const float4*)(xb + (size_t)(k + 8 + i) * HW_);
        }
        PREP_COMP(vB, k + 4);
    }
#undef PREP_COMP

    // FilterNorm over taps (vectorized over 4 px)
    {
        float4 mean = make_float4(0, 0, 0, 0);
#pragma unroll
        for (int t = 0; t < 9; ++t) {
            mean.x += st[t].x; mean.y += st[t].y; mean.z += st[t].z; mean.w += st[t].w;
        }
        mean.x *= (1.f/9.f); mean.y *= (1.f/9.f); mean.z *= (1.f/9.f); mean.w *= (1.f/9.f);
        float4 var = make_float4(0, 0, 0, 0);
#pragma unroll
        for (int t = 0; t < 9; ++t) {
            float dx = st[t].x - mean.x, dy = st[t].y - mean.y;
            float dz = st[t].z - mean.z, dw = st[t].w - mean.w;
            var.x = fmaf(dx, dx, var.x); var.y = fmaf(dy, dy, var.y);
            var.z = fmaf(dz, dz, var.z); var.w = fmaf(dw, dw, var.w);
        }
        float ix = 1.f / (sqrtf(var.x * (1.f/8.f)) + 1e-10f);
        float iy = 1.f / (sqrtf(var.y * (1.f/8.f)) + 1e-10f);
        float iz = 1.f / (sqrtf(var.z * (1.f/8.f)) + 1e-10f);
        float iw = 1.f / (sqrtf(var.w * (1.f/8.f)) + 1e-10f);
        float* sp = sarr + ((size_t)b * 9) * HW_ + pix;
#pragma unroll
        for (int t = 0; t < 9; ++t) {
            float sd = sstd[t];
            *(float4*)(sp + (size_t)t * HW_) = make_float4(
                (st[t].x - mean.x) * ix * sd, (st[t].y - mean.y) * iy * sd,
                (st[t].z - mean.z) * iz * sd, (st[t].w - mean.w) * iw * sd);
        }
    }
    __syncthreads();
    if (threadIdx.x < C_) {
        int c = threadIdx.x;
        float s4 = lg[0][c] + lg[1][c] + lg[2][c] + lg[3][c];
        gp[((size_t)b * C_ + c) * NPB_ + blockIdx.x] = s4;
    }
}

// ------ cfk: reduce gap partials + SE MLP + FilterNorm -> cf (B,C,12 padded) ------
__global__ __launch_bounds__(256) void cfk(const float* __restrict__ gp,
    const float* __restrict__ cw1, const float* __restrict__ cb1,
    const float* __restrict__ cw2, const float* __restrict__ cb2,
    const float* __restrict__ cstd, float* __restrict__ cf) {
    const int tid = threadIdx.x;
    const int b = tid >> 6, c = tid & 63;
    __shared__ float gsm[B_][C_];
    __shared__ float hsm[B_][MID_];
    {
        const float4* p4 = (const float4*)(gp + ((size_t)b * C_ + c) * NPB_);
        float s = 0.f;
#pragma unroll
        for (int i = 0; i < NPB_ / 4; ++i) { float4 v = p4[i]; s += (v.x + v.y) + (v.z + v.w); }
        gsm[b][c] = s * (1.f / HW_);
    }
    __syncthreads();
    if (tid < B_ * MID_) {
        int b2 = tid / MID_, m = tid % MID_;
        float a = cb1[m];
        for (int cc = 0; cc < C_; ++cc) a = fmaf(gsm[b2][cc], cw1[m * C_ + cc], a);
        hsm[b2][m] = fmaxf(a, 0.f);
    }
    __syncthreads();
    float v[9];
    float mean = 0.f;
#pragma unroll
    for (int t = 0; t < 9; ++t) {
        int o = c * 9 + t;
        float a = cb2[o];
#pragma unroll
        for (int m = 0; m < MID_; ++m) a = fmaf(hsm[b][m], cw2[o * MID_ + m], a);
        v[t] = a;
        mean += a;
    }
    mean *= (1.f / 9.f);
    float var = 0.f;
#pragma unroll
    for (int t = 0; t < 9; ++t) { float d = v[t] - mean; var += d * d; }
    float inv = 1.f / (sqrtf(var * (1.f / 8.f)) + 1e-10f);
    float* o12 = cf + ((size_t)b * C_ + c) * 12;
#pragma unroll
    for (int t = 0; t < 9; ++t) o12[t] = (v[t] - mean) * inv * cstd[c * 9 + t];
    o12[9] = 0.f; o12[10] = 0.f; o12[11] = 0.f;
}

// ---------- apply: full-row waves, 4 px/thread, register halo via shfl ----------
// PASS1: grid (64, B), all 64 channels, fused relu + s_next + gap partials.
// PASS2: grid (64, B, 2), 32-channel halves, + residual.
template<bool PASS1>
__global__ __launch_bounds__(256, 1) void apply_kernel(const float* __restrict__ in,
    const float* __restrict__ sarr, const float* __restrict__ cf,
    const float* __restrict__ swn, const float* __restrict__ sbn,
    const float* __restrict__ sstdn, const float* __restrict__ resid,
    float* __restrict__ out, float* __restrict__ snext, float* __restrict__ gpn) {
    const int lane = threadIdx.x & 63, wv = threadIdx.x >> 6;
    const int row = blockIdx.x * 4 + wv;
    const int b = blockIdx.y;
    const int c0 = PASS1 ? 0 : (blockIdx.z * 32);
    const int NCH = PASS1 ? 64 : 32;
    const int pix = row * W_ + lane * 4;
    __shared__ float lg[4][C_];

    const bool rup = row > 0, rdn = row < H_ - 1;
    const int offUp = rup ? -W_ : 0;
    const int offDn = rdn ? W_ : 0;
    const float fup = rup ? 1.f : 0.f;
    const float fdn = rdn ? 1.f : 0.f;

    // per-pixel s taps (float4 over the 4 px); fold ALL edge masks in here
    float4 s0t[9];
    {
        const float* sp = sarr + ((size_t)b * 9) * HW_ + pix;
#pragma unroll
        for (int t = 0; t < 9; ++t) s0t[t] = *(const float4*)(sp + (size_t)t * HW_);
#pragma unroll
        for (int t = 0; t < 3; ++t) {
            s0t[t].x *= fup; s0t[t].y *= fup; s0t[t].z *= fup; s0t[t].w *= fup;
            s0t[t + 6].x *= fdn; s0t[t + 6].y *= fdn; s0t[t + 6].z *= fdn; s0t[t + 6].w *= fdn;
        }
        if (lane == 0)  { s0t[0].x = 0.f; s0t[3].x = 0.f; s0t[6].x = 0.f; }
        if (lane == 63) { s0t[2].w = 0.f; s0t[5].w = 0.f; s0t[8].w = 0.f; }
    }

    float4 nt[9];
    if (PASS1) {
#pragma unroll
        for (int t = 0; t < 9; ++t) { float v = sbn[t]; nt[t] = make_float4(v, v, v, v); }
    }

    const float* inb = in + (size_t)b * C_ * HW_ + pix;
    const float* cfb = cf + ((size_t)b * C_) * 12;
    const float* rb  = PASS1 ? nullptr : (resid + (size_t)b * C_ * HW_ + pix);
    float* outp = out + (size_t)b * C_ * HW_ + pix;

    float4 bufA[4][3], bufB[4][3], rA[4], rB[4];

#define LOADB(BUF, RV, CH0) do {                                              \
        _Pragma("unroll")                                                     \
        for (int i_ = 0; i_ < 4; ++i_) {                                      \
            const float* p_ = inb + (size_t)((CH0) + i_) * HW_;               \
            BUF[i_][0] = *(const float4*)(p_ + offUp);                        \
            BUF[i_][1] = *(const float4*)(p_);                                \
            BUF[i_][2] = *(const float4*)(p_ + offDn);                        \
            if (!PASS1) RV[i_] = *(const float4*)(rb + (size_t)((CH0) + i_) * HW_); \
        }                                                                     \
    } while (0)

#define COMPB(BUF, RV, CH0) do {                                              \
        _Pragma("unroll")                                                     \
        for (int i_ = 0; i_ < 4; ++i_) {                                      \
            const int ch_ = (CH0) + i_;                                       \
            const float* cfc_ = cfb + (size_t)ch_ * 12;                       \
            float4 acc_ = make_float4(0.f, 0.f, 0.f, 0.f);                    \
            _Pragma("unroll")                                                 \
            for (int dr_ = 0; dr_ < 3; ++dr_) {                               \
                float4 v_ = BUF[i_][dr_];                                     \
                float w0_ = __shfl_up(v_.w, 1, 64);                           \
                float w5_ = __shfl_down(v_.x, 1, 64);                         \
                const float w_[6] = {w0_, v_.x, v_.y, v_.z, v_.w, w5_};       \
                _Pragma("unroll")                                             \
                for (int dc_ = 0; dc_ < 3; ++dc_) {                           \
                    const int t_ = dr_ * 3 + dc_;                             \
                    const float cft_ = cfc_[t_];                              \
                    acc_.x = fmaf(w_[dc_ + 0] * s0t[t_].x, cft_, acc_.x);     \
                    acc_.y = fmaf(w_[dc_ + 1] * s0t[t_].y, cft_, acc_.y);     \
                    acc_.z = fmaf(w_[dc_ + 2] * s0t[t_].z, cft_, acc_.z);     \
                    acc_.w = fmaf(w_[dc_ + 3] * s0t[t_].w, cft_, acc_.w);     \
                }                                                             \
            }                                                                 \
            float4 o_;                                                        \
            if (PASS1) {                                                      \
                o_.x = fmaxf(acc_.x, 0.f); o_.y = fmaxf(acc_.y, 0.f);         \
                o_.z = fmaxf(acc_.z, 0.f); o_.w = fmaxf(acc_.w, 0.f);         \
                _Pragma("unroll")                                             \
                for (int t_ = 0; t_ < 9; ++t_) {                              \
                    const float wt_ = swn[t_ * C_ + ch_];                     \
                    nt[t_].x = fmaf(o_.x, wt_, nt[t_].x);                     \
                    nt[t_].y = fmaf(o_.y, wt_, nt[t_].y);                     \
                    nt[t_].z = fmaf(o_.z, wt_, nt[t_].z);                     \
                    nt[t_].w = fmaf(o_.w, wt_, nt[t_].w);                     \
                }                                                             \
                float g_ = wave_reduce64(((o_.x + o_.y) + (o_.z + o_.w)));    \
                if (lane == 0) lg[wv][ch_] = g_;                              \
            } else {                                                          \
                o_.x = acc_.x + RV[i_].x; o_.y = acc_.y + RV[i_].y;           \
                o_.z = acc_.z + RV[i_].z; o_.w = acc_.w + RV[i_].w;           \
            }                                                                 \
            *(float4*)(outp + (size_t)ch_ * HW_) = o_;                        \
        }                                                                     \
    } while (0)

    LOADB(bufA, rA, c0);
    for (int k = c0; k < c0 + NCH; k += 8) {
        LOADB(bufB, rB, k + 4);
        COMPB(bufA, rA, k);
        if (k + 8 < c0 + NCH) LOADB(bufA, rA, k + 8);
        COMPB(bufB, rB, k + 4);
    }
#undef LOADB
#undef COMPB

    if (PASS1) {
        // FilterNorm on nt (vectorized over 4 px) + store s_next
        float4 mean = make_float4(0, 0, 0, 0);
#pragma unroll
        for (int t = 0; t < 9; ++t) {
            mean.x += nt[t].x; mean.y += nt[t].y; mean.z += nt[t].z; mean.w += nt[t].w;
        }
        mean.x *= (1.f/9.f); mean.y *= (1.f/9.f); mean.z *= (1.f/9.f); mean.w *= (1.f/9.f);
        float4 var = make_float4(0, 0, 0, 0);
#pragma unroll
        for (int t = 0; t < 9; ++t) {
            float dx = nt[t].x - mean.x, dy = nt[t].y - mean.y;
            float dz = nt[t].z - mean.z, dw = nt[t].w - mean.w;
            var.x = fmaf(dx, dx, var.x); var.y = fmaf(dy, dy, var.y);
            var.z = fmaf(dz, dz, var.z); var.w = fmaf(dw, dw, var.w);
        }
        float ix = 1.f / (sqrtf(var.x * (1.f/8.f)) + 1e-10f);
        float iy = 1.f / (sqrtf(var.y * (1.f/8.f)) + 1e-10f);
        float iz = 1.f / (sqrtf(var.z * (1.f/8.f)) + 1e-10f);
        float iw = 1.f / (sqrtf(var.w * (1.f/8.f)) + 1e-10f);
        float* sp = snext + ((size_t)b * 9) * HW_ + pix;
#pragma unroll
        for (int t = 0; t < 9; ++t) {
            float sd = sstdn[t];
            *(float4*)(sp + (size_t)t * HW_) = make_float4(
                (nt[t].x - mean.x) * ix * sd, (nt[t].y - mean.y) * iy * sd,
                (nt[t].z - mean.z) * iz * sd, (nt[t].w - mean.w) * iw * sd);
        }
        __syncthreads();
        if (threadIdx.x < C_) {
            int c = threadIdx.x;
            float s4 = lg[0][c] + lg[1][c] + lg[2][c] + lg[3][c];
            gpn[((size_t)b * C_ + c) * NPB_ + blockIdx.x] = s4;
        }
    }
}

extern "C" void kernel_launch(void* const* d_in, const int* in_sizes, int n_in,
                              void* d_out, int out_size, void* d_ws, size_t ws_size,
                              hipStream_t stream) {
    const float* x     = (const float*)d_in[0];
    const float* sw1   = (const float*)d_in[1];
    const float* sb1   = (const float*)d_in[2];
    const float* sstd1 = (const float*)d_in[3];
    const float* cw1_1 = (const float*)d_in[4];
    const float* cb1_1 = (const float*)d_in[5];
    const float* cw2_1 = (const float*)d_in[6];
    const float* cb2_1 = (const float*)d_in[7];
    const float* cstd1 = (const float*)d_in[8];
    const float* sw2   = (const float*)d_in[9];
    const float* sb2   = (const float*)d_in[10];
    const float* sstd2 = (const float*)d_in[11];
    const float* cw1_2 = (const float*)d_in[12];
    const float* cb1_2 = (const float*)d_in[13];
    const float* cw2_2 = (const float*)d_in[14];
    const float* cb2_2 = (const float*)d_in[15];
    const float* cstd2 = (const float*)d_in[16];
    float* outp = (float*)d_out;

    const size_t n_out1 = (size_t)B_ * C_ * HW_;     // 16,777,216
    const size_t n_s    = (size_t)B_ * 9 * HW_;      // 2,359,296
    const size_t n_cf   = (size_t)B_ * C_ * 12;      // 3,072 (padded)
    const size_t n_gp   = (size_t)B_ * C_ * NPB_;    // 16,384
    const size_t need = (n_out1 + 2 * n_s + 2 * n_cf + 2 * n_gp) * sizeof(float);
    if (ws_size < need) return;

    float* out1 = (float*)d_ws;
    float* s1   = out1 + n_out1;
    float* s2   = s1 + n_s;
    float* cf1  = s2 + n_s;
    float* cf2  = cf1 + n_cf;
    float* gp1  = cf2 + n_cf;
    float* gp2  = gp1 + n_gp;

    dim3 g1(H_ / 4, B_);        // 256 blocks, wave = full row
    dim3 g2(H_ / 4, B_, 2);     // 512 blocks, 32-channel halves

    prep_kernel<<<g1, 256, 0, stream>>>(x, sw1, sb1, sstd1, s1, gp1);
    cfk<<<1, 256, 0, stream>>>(gp1, cw1_1, cb1_1, cw2_1, cb2_1, cstd1, cf1);
    apply_kernel<true><<<g1, 256, 0, stream>>>(x, s1, cf1, sw2, sb2, sstd2,
                                               nullptr, out1, s2, gp2);
    cfk<<<1, 256, 0, stream>>>(gp2, cw1_2, cb1_2, cw2_2, cb2_2, cstd2, cf2);
    apply_kernel<false><<<g2, 256, 0, stream>>>(out1, s2, cf2, nullptr, nullptr,
                                                nullptr, x, outp, nullptr, nullptr);
}